// Round 11
// baseline (291.985 us; speedup 1.0000x reference)
//
#include <hip/hip_runtime.h>

#define L  2048
#define D  64
#define NH 16
#define NB 2
#define KT 64
#define NT 32
#define LOG2E 1.44269504088896f

using half8   = _Float16 __attribute__((ext_vector_type(8)));
using half4v  = _Float16 __attribute__((ext_vector_type(4)));
using float4v = float    __attribute__((ext_vector_type(4)));
using int4v   = int      __attribute__((ext_vector_type(4)));

#define BAR()    asm volatile("s_barrier" ::: "memory")
#define WAITV(n) asm volatile("s_waitcnt vmcnt(" #n ")" ::: "memory")
#define WAITL()  asm volatile("s_waitcnt lgkmcnt(0)" ::: "memory")

__device__ __forceinline__ void gload16(const void* g, void* l) {
    __builtin_amdgcn_global_load_lds((const __attribute__((address_space(1))) void*)g,
                                     (__attribute__((address_space(3))) void*)l, 16, 0, 0);
}
__device__ __forceinline__ void gload4(const void* g, void* l) {
    __builtin_amdgcn_global_load_lds((const __attribute__((address_space(1))) void*)g,
                                     (__attribute__((address_space(3))) void*)l, 4, 0, 0);
}

// ---------------- precompute: qh = fp16(q * log2e/8), kh = fp16(k) ----------------
__global__ __launch_bounds__(256) void prep_qk(const float* __restrict__ q,
                                               const float* __restrict__ k,
                                               _Float16* __restrict__ qh,
                                               _Float16* __restrict__ kh) {
    int i = (blockIdx.x * 256 + threadIdx.x) * 8;
    float4v a0 = *(const float4v*)(q + i);
    float4v a1 = *(const float4v*)(q + i + 4);
    float4v b0 = *(const float4v*)(k + i);
    float4v b1 = *(const float4v*)(k + i + 4);
    half8 qo, ko;
    const float s = 0.125f * LOG2E;
#pragma unroll
    for (int j = 0; j < 4; ++j) {
        qo[j]     = (_Float16)(a0[j] * s);
        qo[4 + j] = (_Float16)(a1[j] * s);
        ko[j]     = (_Float16)b0[j];
        ko[4 + j] = (_Float16)b1[j];
    }
    *(half8*)(qh + i) = qo;
    *(half8*)(kh + i) = ko;
}

// ---------------- precompute: vt[b,h,d,l] = fp16(v[b,h,l,d]) ----------------
__global__ __launch_bounds__(256) void prep_vt(const float* __restrict__ v,
                                               _Float16* __restrict__ vt) {
    __shared__ float tile[64][65];
    int bh = blockIdx.x >> 5;
    int l0 = (blockIdx.x & 31) * 64;
    const float* vb = v + (size_t)bh * L * D + (size_t)l0 * D;
    int row = threadIdx.x >> 2, c0 = (threadIdx.x & 3) * 16;
#pragma unroll
    for (int j = 0; j < 16; j += 4) {
        float4v t4 = *(const float4v*)(vb + row * D + c0 + j);
        tile[row][c0 + j + 0] = t4[0];
        tile[row][c0 + j + 1] = t4[1];
        tile[row][c0 + j + 2] = t4[2];
        tile[row][c0 + j + 3] = t4[3];
    }
    __syncthreads();
    int d = threadIdx.x >> 2, lq = (threadIdx.x & 3) * 16;
    _Float16* ob = vt + (size_t)bh * D * L + (size_t)d * L + l0 + lq;
    half8 o0, o1;
#pragma unroll
    for (int j = 0; j < 8; ++j) {
        o0[j] = (_Float16)tile[lq + j][d];
        o1[j] = (_Float16)tile[lq + 8 + j][d];
    }
    *(half8*)(ob)     = o0;
    *(half8*)(ob + 8) = o1;
}

// ------- precompute: mbh = fp16(mask ? bias*log2e : -1500) -------
__global__ __launch_bounds__(256) void prep_mbh(const int* __restrict__ mask,
                                                const float* __restrict__ bias,
                                                _Float16* __restrict__ mbh) {
    int i = (blockIdx.x * 256 + threadIdx.x) * 8;
    half8 o;
#pragma unroll
    for (int j = 0; j < 8; j += 4) {
        int4v   m = *(const int4v*)(mask + i + j);
        float4v b = *(const float4v*)(bias + i + j);
        o[j + 0] = (_Float16)(m[0] ? b[0] * LOG2E : -1500.0f);
        o[j + 1] = (_Float16)(m[1] ? b[1] * LOG2E : -1500.0f);
        o[j + 2] = (_Float16)(m[2] ? b[2] * LOG2E : -1500.0f);
        o[j + 3] = (_Float16)(m[3] ? b[3] * LOG2E : -1500.0f);
    }
    *(half8*)(mbh + i) = o;
}

// ---------------- kernel L: row sums -> rls = 1/l ----------------
// R10 loop-1 minus V/puh/PV. block = 16 q-rows, 4 waves, wave owns the
// 16-key quarter of each 64-key tile; wave-private K/M staging, dbuf,
// barrier-free. Small LDS (20.5KB) + ~50 VGPR -> ~7 blocks/CU TLP.
__global__ __launch_bounds__(256, 4) void attn_lsum(const _Float16* __restrict__ qh,
                                                    const _Float16* __restrict__ kh,
                                                    const _Float16* __restrict__ mbh,
                                                    float* __restrict__ rls_g) {
    __shared__ _Float16 kbufL[4][2][1024];   // [w][bs][16key x 64d] XOR-swz
    __shared__ _Float16 mbufL[4][2][256];    // [w][bs][16row x 16key]
    __shared__ float lpart[4][16];

    int p  = blockIdx.x;
    int l  = (p & 7) * 512 + (p >> 3);
    int b  = l >> 11, h = (l >> 7) & 15, qt = l & 127;
    int bh = b * NH + h;
    int q0 = qt * 16;

    int tid = threadIdx.x, w = tid >> 6, lane = tid & 63;
    int cg = lane & 15, grp = lane >> 4;

    const _Float16* kg = kh  + (size_t)bh * L * D;
    const _Float16* mg = mbh + ((size_t)b * L + q0) * L;
    const _Float16* qg = qh  + ((size_t)bh * L + q0) * D;

    half8 aq0 = *(const half8*)(qg + cg * D + grp * 8);
    half8 aq1 = *(const half8*)(qg + cg * D + 32 + grp * 8);

    const int r8  = lane >> 3;
    const int kch = ((lane & 7) ^ r8) * 8;
    const int mkey = (lane & 7) * 2;

    auto stage = [&](int t, int bs) {
        int k0 = t * KT + 16 * w;
        _Float16* kd = &kbufL[w][bs][0];
        gload16(kg + (size_t)(k0 +     r8) * D + kch, kd);
        gload16(kg + (size_t)(k0 + 8 + r8) * D + kch, kd + 512);
        _Float16* md = &mbufL[w][bs][0];
        gload4(mg + (size_t)(r8)     * L + k0 + mkey, md);
        gload4(mg + (size_t)(8 + r8) * L + k0 + mkey, md + 128);
    };

    const int kro = cg * 64;
    const int ks0 = ((grp)     ^ (cg & 7)) * 8;
    const int ks1 = ((4 + grp) ^ (cg & 7)) * 8;
    const int mro = cg * 16 + grp * 4;

    float ls = 0.f;
    stage(0, 0);
#pragma unroll
    for (int t = 0; t < NT; ++t) {
        const int bs = t & 1;
        if (t + 1 < NT) { stage(t + 1, bs ^ 1); WAITV(4); }
        else            { WAITV(0); }
        const _Float16* kb = &kbufL[w][bs][0];
        const _Float16* mb = &mbufL[w][bs][0];
        half8  bk0 = *(const half8*)(kb + kro + ks0);
        half8  bk1 = *(const half8*)(kb + kro + ks1);
        half4v m4  = *(const half4v*)(mb + mro);
        float4v acc;
        acc[0] = (float)m4[0]; acc[1] = (float)m4[1];
        acc[2] = (float)m4[2]; acc[3] = (float)m4[3];
        __builtin_amdgcn_s_setprio(1);
        acc = __builtin_amdgcn_mfma_f32_16x16x32_f16(bk0, aq0, acc, 0, 0, 0);
        acc = __builtin_amdgcn_mfma_f32_16x16x32_f16(bk1, aq1, acc, 0, 0, 0);
        __builtin_amdgcn_s_setprio(0);
        ls += (exp2f(acc[0]) + exp2f(acc[1])) + (exp2f(acc[2]) + exp2f(acc[3]));
    }

    ls += __shfl_xor(ls, 16);
    ls += __shfl_xor(ls, 32);
    if (grp == 0) lpart[w][cg] = ls;
    __syncthreads();
    if (tid < 16) {
        float lt = (lpart[0][tid] + lpart[1][tid]) + (lpart[2][tid] + lpart[3][tid]);
        rls_g[(size_t)bh * L + q0 + tid] = 1.0f / lt;
    }
}

// ---------------- main: single loop, stores co-issued with staging ----------------
// rl known upfront (rls_g). block = 16 q-rows, 4 waves, wave owns key-quarter.
// Per 64-key tile: stage K/V (wave-private dbuf gload_lds) + reg-prefetch M
// -> QK -> pn = e*rl -> normalized fp16 p feeds PV directly -> t32 LDS bounce
// (dbuf, 1 barrier/iter) -> 256B-contiguous NT attn stores. Loads AND stores
// in flight every iteration; vmcnt ledger: stage(4)+mload(1)+NTstore(1)=6.
__global__ __launch_bounds__(256, 4) void attn_main(const _Float16* __restrict__ qh,
                                                    const _Float16* __restrict__ kh,
                                                    const _Float16* __restrict__ vt,
                                                    const _Float16* __restrict__ mbh,
                                                    const float* __restrict__ rls_g,
                                                    float* __restrict__ out_ho,
                                                    float* __restrict__ out_attn) {
    // [0,16K) kbuf [w][bs][16key x 64d] | [16K,32K) vbuf [w][bs][64d x 16key]
    // [32K,40K) t32 dbuf [2][16][64] f32 | post-loop: ored [4][16][68] aliases [0,17.4K)
    __shared__ __align__(16) char arena[40960];

    int p  = blockIdx.x;
    int l  = (p & 7) * 512 + (p >> 3);
    int b  = l >> 11, h = (l >> 7) & 15, qt = l & 127;
    int bh = b * NH + h;
    int q0 = qt * 16;

    int tid = threadIdx.x, w = tid >> 6, lane = tid & 63;
    int cg = lane & 15, grp = lane >> 4;

    const _Float16* kg = kh  + (size_t)bh * L * D;
    const _Float16* vg = vt  + (size_t)bh * D * L;
    const _Float16* mg = mbh + ((size_t)b * L + q0) * L;
    const _Float16* qg = qh  + ((size_t)bh * L + q0) * D;

    const float rl = rls_g[(size_t)bh * L + q0 + cg];   // 1/l for q-row cg

    half8 aq0 = *(const half8*)(qg + cg * D + grp * 8);
    half8 aq1 = *(const half8*)(qg + cg * D + 32 + grp * 8);

    _Float16* kbw = (_Float16*)(arena)         + w * 2048;
    _Float16* vbw = (_Float16*)(arena + 16384) + w * 2048;
    float*    t32 = (float*)(arena + 32768);             // dbuf [2][16][64]

    const int r8   = lane >> 3;
    const int kch  = ((lane & 7) ^ r8) * 8;
    const int vrow = lane >> 1, vkh = (lane & 1) * 8;

    auto stage = [&](int t, int bs) {
        int k0 = t * KT + 16 * w;
        _Float16* kd = kbw + bs * 1024;
        gload16(kg + (size_t)(k0 +     r8) * D + kch, kd);
        gload16(kg + (size_t)(k0 + 8 + r8) * D + kch, kd + 512);
        _Float16* vd = vbw + bs * 1024;
        gload16(vg + (size_t)(vrow)      * L + k0 + vkh, vd);
        gload16(vg + (size_t)(32 + vrow) * L + k0 + vkh, vd + 512);
    };

    const int kro = cg * 64;
    const int ks0 = ((grp)     ^ (cg & 7)) * 8;
    const int ks1 = ((4 + grp) ^ (cg & 7)) * 8;
    const int vro = grp * 4;
    const _Float16* mrow = mg + (size_t)cg * L + 16 * w + grp * 4;

    const int t32wo = cg * 64 + (((w * 4 + grp) ^ (cg & 7)) * 4);
    const int swrow = tid >> 4, jj = tid & 15;
    const int t32ro = swrow * 64 + ((jj ^ (swrow & 7)) * 4);
    float* arow = out_attn + ((size_t)bh * L + q0) * L;

    float4v oa0 = {0.f,0.f,0.f,0.f}, oa1 = {0.f,0.f,0.f,0.f};
    float4v oa2 = {0.f,0.f,0.f,0.f}, oa3 = {0.f,0.f,0.f,0.f};

    half4v mcur = *(const half4v*)(mrow);
    stage(0, 0);
#pragma unroll
    for (int t = 0; t < NT; ++t) {
        const int bs = t & 1;
        half4v mnxt = mcur;
        if (t + 1 < NT) {
            stage(t + 1, bs ^ 1);
            mnxt = *(const half4v*)(mrow + (t + 1) * KT);
        }
        // ledger: NTstore(t-1)[1] + stage(t+1)[4] + mload(t+1)[1] stay in flight
        if (t == 0)           { WAITV(5); }
        else if (t + 1 < NT)  { WAITV(6); }
        else                  { WAITV(1); }

        const _Float16* kb = kbw + bs * 1024;
        const _Float16* vb = vbw + bs * 1024;
        half8 bk0 = *(const half8*)(kb + kro + ks0);
        half8 bk1 = *(const half8*)(kb + kro + ks1);
        float4v acc;
        acc[0] = (float)mcur[0]; acc[1] = (float)mcur[1];
        acc[2] = (float)mcur[2]; acc[3] = (float)mcur[3];
        __builtin_amdgcn_s_setprio(1);
        acc = __builtin_amdgcn_mfma_f32_16x16x32_f16(bk0, aq0, acc, 0, 0, 0);
        acc = __builtin_amdgcn_mfma_f32_16x16x32_f16(bk1, aq1, acc, 0, 0, 0);
        __builtin_amdgcn_s_setprio(0);
        float4v pn;
        pn[0] = exp2f(acc[0]) * rl; pn[1] = exp2f(acc[1]) * rl;
        pn[2] = exp2f(acc[2]) * rl; pn[3] = exp2f(acc[3]) * rl;
        float* tb = t32 + (t & 1) * 1024;
        *(float4v*)(tb + t32wo) = pn;                      // store-path bounce
        half4v ph;                                         // normalized p, fp16
        ph[0] = (_Float16)pn[0]; ph[1] = (_Float16)pn[1];
        ph[2] = (_Float16)pn[2]; ph[3] = (_Float16)pn[3];
        half4v pv0 = *(const half4v*)(vb + (cg +  0) * 16 + vro);
        half4v pv1 = *(const half4v*)(vb + (cg + 16) * 16 + vro);
        half4v pv2 = *(const half4v*)(vb + (cg + 32) * 16 + vro);
        half4v pv3 = *(const half4v*)(vb + (cg + 48) * 16 + vro);
        __builtin_amdgcn_s_setprio(1);
        oa0 = __builtin_amdgcn_mfma_f32_16x16x16f16(ph, pv0, oa0, 0, 0, 0);
        oa1 = __builtin_amdgcn_mfma_f32_16x16x16f16(ph, pv1, oa1, 0, 0, 0);
        oa2 = __builtin_amdgcn_mfma_f32_16x16x16f16(ph, pv2, oa2, 0, 0, 0);
        oa3 = __builtin_amdgcn_mfma_f32_16x16x16f16(ph, pv3, oa3, 0, 0, 0);
        __builtin_amdgcn_s_setprio(0);
        WAITL();                                   // t32 ds_write drained
        BAR();                                     // all waves' quarters visible
        float4v s = *(const float4v*)(tb + t32ro);
        __builtin_nontemporal_store(s, (float4v*)(arow + (size_t)swrow * L + t * KT + jj * 4));
        mcur = mnxt;
    }

    // ---------------- O reduce across waves (normalized already) ----------------
    __syncthreads();
    float* ored = (float*)arena;                   // [4][16][68], aliases k/v bufs
    float* orw  = ored + w * (16 * 68);
#pragma unroll
    for (int r = 0; r < 4; ++r) {
        orw[(grp * 4 + r) * 68 +  0 + cg] = oa0[r];
        orw[(grp * 4 + r) * 68 + 16 + cg] = oa1[r];
        orw[(grp * 4 + r) * 68 + 32 + cg] = oa2[r];
        orw[(grp * 4 + r) * 68 + 48 + cg] = oa3[r];
    }
    __syncthreads();
    int qr = tid >> 4, d4 = (tid & 15) * 4;
    float4v s0 = *(const float4v*)(ored + 0 * 1088 + qr * 68 + d4);
    float4v s1 = *(const float4v*)(ored + 1 * 1088 + qr * 68 + d4);
    float4v s2 = *(const float4v*)(ored + 2 * 1088 + qr * 68 + d4);
    float4v s3 = *(const float4v*)(ored + 3 * 1088 + qr * 68 + d4);
    float4v oo;
    oo[0] = (s0[0] + s1[0]) + (s2[0] + s3[0]);
    oo[1] = (s0[1] + s1[1]) + (s2[1] + s3[1]);
    oo[2] = (s0[2] + s1[2]) + (s2[2] + s3[2]);
    oo[3] = (s0[3] + s1[3]) + (s2[3] + s3[3]);
    __builtin_nontemporal_store(oo, (float4v*)(out_ho + ((size_t)bh * L + q0 + qr) * D + d4));
}

extern "C" void kernel_launch(void* const* d_in, const int* in_sizes, int n_in,
                              void* d_out, int out_size, void* d_ws, size_t ws_size,
                              hipStream_t stream) {
    const float* q    = (const float*)d_in[0];
    const float* k    = (const float*)d_in[1];
    const float* v    = (const float*)d_in[2];
    const int*   mask = (const int*)d_in[3];
    const float* bias = (const float*)d_in[4];

    float* ho   = (float*)d_out;
    float* attn = (float*)d_out + (size_t)NB * NH * L * D;

    char* ws = (char*)d_ws;
    _Float16* qh  = (_Float16*)(ws);                       //  8 MB
    _Float16* kh  = (_Float16*)(ws + ((size_t)8  << 20));  //  8 MB
    _Float16* vt  = (_Float16*)(ws + ((size_t)16 << 20));  //  8 MB
    _Float16* mbh = (_Float16*)(ws + ((size_t)24 << 20));  // 16 MB
    float*    rls = (float*)   (ws + ((size_t)40 << 20));  // 256 KB
    (void)in_sizes; (void)n_in; (void)out_size; (void)ws_size;

    prep_qk<<<2048, 256, 0, stream>>>(q, k, qh, kh);
    prep_vt<<<1024, 256, 0, stream>>>(v, vt);
    prep_mbh<<<4096, 256, 0, stream>>>(mask, bias, mbh);
    attn_lsum<<<4096, 256, 0, stream>>>(qh, kh, mbh, rls);
    attn_main<<<4096, 256, 0, stream>>>(qh, kh, vt, mbh, rls, ho, attn);
}

// Round 12
// 207.624 us; speedup vs baseline: 1.4063x; 1.4063x over previous
//
#include <hip/hip_runtime.h>

#define L  2048
#define D  64
#define NH 16
#define NB 2
#define KT 64
#define NT 32
#define LOG2E 1.44269504088896f

using half8   = _Float16 __attribute__((ext_vector_type(8)));
using half4v  = _Float16 __attribute__((ext_vector_type(4)));
using float4v = float    __attribute__((ext_vector_type(4)));
using int4v   = int      __attribute__((ext_vector_type(4)));

#define BAR()    asm volatile("s_barrier" ::: "memory")
#define WAITV(n) asm volatile("s_waitcnt vmcnt(" #n ")" ::: "memory")
#define WAITL()  asm volatile("s_waitcnt lgkmcnt(0)" ::: "memory")

__device__ __forceinline__ void gload16(const void* g, void* l) {
    __builtin_amdgcn_global_load_lds((const __attribute__((address_space(1))) void*)g,
                                     (__attribute__((address_space(3))) void*)l, 16, 0, 0);
}
__device__ __forceinline__ void gload4(const void* g, void* l) {
    __builtin_amdgcn_global_load_lds((const __attribute__((address_space(1))) void*)g,
                                     (__attribute__((address_space(3))) void*)l, 4, 0, 0);
}

// ---------------- precompute: qh = fp16(q * log2e/8), kh = fp16(k) ----------------
__global__ __launch_bounds__(256) void prep_qk(const float* __restrict__ q,
                                               const float* __restrict__ k,
                                               _Float16* __restrict__ qh,
                                               _Float16* __restrict__ kh) {
    int i = (blockIdx.x * 256 + threadIdx.x) * 8;
    float4v a0 = *(const float4v*)(q + i);
    float4v a1 = *(const float4v*)(q + i + 4);
    float4v b0 = *(const float4v*)(k + i);
    float4v b1 = *(const float4v*)(k + i + 4);
    half8 qo, ko;
    const float s = 0.125f * LOG2E;
#pragma unroll
    for (int j = 0; j < 4; ++j) {
        qo[j]     = (_Float16)(a0[j] * s);
        qo[4 + j] = (_Float16)(a1[j] * s);
        ko[j]     = (_Float16)b0[j];
        ko[4 + j] = (_Float16)b1[j];
    }
    *(half8*)(qh + i) = qo;
    *(half8*)(kh + i) = ko;
}

// ------- precompute: vt2[bh][kb(128)][d(64)][kl(16)] = fp16(v[b,h,kb*16+kl,d]) -------
// Each (kb,d) row of 16 keys is contiguous: wave staging = contiguous 2KB.
__global__ __launch_bounds__(256) void prep_vt(const float* __restrict__ v,
                                               _Float16* __restrict__ vt) {
    __shared__ float tile[64][65];
    int bh = blockIdx.x >> 5;
    int l0 = (blockIdx.x & 31) * 64;
    const float* vb = v + (size_t)bh * L * D + (size_t)l0 * D;
    int row = threadIdx.x >> 2, c0 = (threadIdx.x & 3) * 16;
#pragma unroll
    for (int j = 0; j < 16; j += 4) {
        float4v t4 = *(const float4v*)(vb + row * D + c0 + j);
        tile[row][c0 + j + 0] = t4[0];
        tile[row][c0 + j + 1] = t4[1];
        tile[row][c0 + j + 2] = t4[2];
        tile[row][c0 + j + 3] = t4[3];
    }
    __syncthreads();
    int d = threadIdx.x >> 2, kbl = threadIdx.x & 3;
    int lq = kbl * 16;
    _Float16* ob = vt + (((size_t)bh * 128 + (l0 >> 4) + kbl) * 64 + d) * 16;
    half8 o0, o1;
#pragma unroll
    for (int j = 0; j < 8; ++j) {
        o0[j] = (_Float16)tile[lq + j][d];
        o1[j] = (_Float16)tile[lq + 8 + j][d];
    }
    *(half8*)(ob)     = o0;     // kl 0..7
    *(half8*)(ob + 8) = o1;     // kl 8..15
}

// ------- precompute: mbh2[b][qt(128)][t(32)][w(4)][row(16)][kl(16)] -------
// = fp16(mask ? bias*log2e : -1500) tiled so each wave's 16x16 M subtile is
// one contiguous 512B block.
__global__ __launch_bounds__(256) void prep_mbh(const int* __restrict__ mask,
                                                const float* __restrict__ bias,
                                                _Float16* __restrict__ mbh) {
    int bq = blockIdx.x;                    // b*128 + qt
    int b  = bq >> 7, qt = bq & 127;
    int row = threadIdx.x >> 4;             // 0..15
    int c16 = threadIdx.x & 15;             // 4-key chunk 0..15 within 64-key tile
    const int*   mrow = mask + ((size_t)b * L + qt * 16 + row) * L;
    const float* brow = bias + ((size_t)b * L + qt * 16 + row) * L;
    _Float16* obase = mbh + (size_t)bq * 32768 + (c16 >> 2) * 256 + row * 16 + (c16 & 3) * 4;
#pragma unroll 4
    for (int t = 0; t < 32; ++t) {
        int key = t * 64 + c16 * 4;
        int4v   m  = *(const int4v*)(mrow + key);
        float4v bb = *(const float4v*)(brow + key);
        half4v o;
        o[0] = m[0] ? (_Float16)(bb[0] * LOG2E) : (_Float16)(-1500.0f);
        o[1] = m[1] ? (_Float16)(bb[1] * LOG2E) : (_Float16)(-1500.0f);
        o[2] = m[2] ? (_Float16)(bb[2] * LOG2E) : (_Float16)(-1500.0f);
        o[3] = m[3] ? (_Float16)(bb[3] * LOG2E) : (_Float16)(-1500.0f);
        *(half4v*)(obase + t * 1024) = o;
    }
}

// ---------------- fused attention (R10 structure, contiguous staging) ----------------
// block = 16 q-rows, 4 waves; wave w owns key-block kb = t*4+w of every
// 64-key tile; wave-private dbuf staging, barrier-free loop 1.
// Loop 1: stage K(2x1KB contig)+V(2x1KB contig)+M(2x256B contig) -> QK ->
//   e=exp2 -> puh[t] fp16 regs -> PV accumulate (unnormalized).
// Loop 2: attn stores only: puh*rl -> t32 LDS dbuf -> 256B-contig NT stores.
__global__ __launch_bounds__(256, 4) void attn_fused(const _Float16* __restrict__ qh,
                                                     const _Float16* __restrict__ kh,
                                                     const _Float16* __restrict__ vt,
                                                     const _Float16* __restrict__ mbh,
                                                     float* __restrict__ out_ho,
                                                     float* __restrict__ out_attn) {
    // [0,16K) kbuf [w][bs][16key x 64d] | [16K,32K) vbuf [w][bs][64d x 16kl]
    // [32K,36K) mbuf [w][bs][16row x 16kl]
    // post-loop1 aliases: t32 dbuf [2][16][64] f32 at [0,8K); ored [4][16][68] at [8K,25.4K)
    __shared__ __align__(16) char arena[36864];
    __shared__ float lpart[4][16];
    __shared__ float rls[16];

    int p  = blockIdx.x;                  // XCD x: 4 heads of one b, all q-tiles
    int l  = (p & 7) * 512 + (p >> 3);
    int b  = l >> 11, h = (l >> 7) & 15, qt = l & 127;
    int bh = b * NH + h;
    int q0 = qt * 16;

    int tid = threadIdx.x, w = tid >> 6, lane = tid & 63;
    int cg = lane & 15, grp = lane >> 4;

    const _Float16* kg = kh  + (size_t)bh * L * D;            // [l][d]
    const _Float16* vg = vt  + (size_t)bh * 131072;           // [kb][d][kl]
    const _Float16* mg = mbh + (size_t)(b * 128 + qt) * 32768; // [t][w][row][kl]
    const _Float16* qg = qh  + ((size_t)bh * L + q0) * D;

    half8 aq0 = *(const half8*)(qg + cg * D + grp * 8);
    half8 aq1 = *(const half8*)(qg + cg * D + 32 + grp * 8);

    _Float16* kbw = (_Float16*)(arena)         + w * 2048;    // 2 bufs x 1024 halfs
    _Float16* vbw = (_Float16*)(arena + 16384) + w * 2048;
    _Float16* mbw = (_Float16*)(arena + 32768) + w * 512;     // 2 bufs x 256 halfs

    const int r8  = lane >> 3;                    // 0..7
    const int kch = ((lane & 7) ^ r8) * 8;        // K src d-chunk, XOR-preswizzled

    auto stage = [&](int t, int bs) {
        int kb = t * 4 + w;                       // wave's key-block
        int k0 = kb * 16;
        _Float16* kd = kbw + bs * 1024;
        gload16(kg + (size_t)(k0 +     r8) * D + kch, kd);
        gload16(kg + (size_t)(k0 + 8 + r8) * D + kch, kd + 512);
        _Float16* vd = vbw + bs * 1024;
        const _Float16* vs = vg + (size_t)kb * 1024;
        gload16(vs + lane * 8, vd);               // contiguous 1KB
        gload16(vs + 512 + lane * 8, vd + 512);   // contiguous 1KB
        _Float16* md = mbw + bs * 256;
        const _Float16* ms = mg + (size_t)t * 1024 + w * 256;
        gload4(ms + lane * 2, md);                // contiguous 256B
        gload4(ms + 128 + lane * 2, md + 128);    // contiguous 256B
    };

    const int kro = cg * 64;
    const int ks0 = ((grp)     ^ (cg & 7)) * 8;
    const int ks1 = ((4 + grp) ^ (cg & 7)) * 8;
    const int mro = cg * 16 + grp * 4;            // M[row cg][kl grp*4..]
    const int vro = grp * 4;

    half4v puh[NT];                               // unnormalized e * 2^-5
    float ls = 0.f;
    float4v oa0 = {0.f,0.f,0.f,0.f}, oa1 = {0.f,0.f,0.f,0.f};
    float4v oa2 = {0.f,0.f,0.f,0.f}, oa3 = {0.f,0.f,0.f,0.f};

    // ---------------- loop 1: barrier-free QK + PV ----------------
    stage(0, 0);
#pragma unroll
    for (int t = 0; t < NT; ++t) {
        const int bs = t & 1;
        if (t + 1 < NT) { stage(t + 1, bs ^ 1); WAITV(6); }
        else            { WAITV(0); }
        const _Float16* kb = kbw + bs * 1024;
        const _Float16* mb = mbw + bs * 256;
        const _Float16* vb = vbw + bs * 1024;
        half8  bk0 = *(const half8*)(kb + kro + ks0);
        half8  bk1 = *(const half8*)(kb + kro + ks1);
        half4v m4  = *(const half4v*)(mb + mro);
        float4v acc;
        acc[0] = (float)m4[0]; acc[1] = (float)m4[1];
        acc[2] = (float)m4[2]; acc[3] = (float)m4[3];
        __builtin_amdgcn_s_setprio(1);
        acc = __builtin_amdgcn_mfma_f32_16x16x32_f16(bk0, aq0, acc, 0, 0, 0);
        acc = __builtin_amdgcn_mfma_f32_16x16x32_f16(bk1, aq1, acc, 0, 0, 0);
        __builtin_amdgcn_s_setprio(0);
        float e0 = exp2f(acc[0]), e1 = exp2f(acc[1]);
        float e2 = exp2f(acc[2]), e3 = exp2f(acc[3]);
        ls += (e0 + e1) + (e2 + e3);
        half4v ph;
        ph[0] = (_Float16)(e0 * 0.03125f); ph[1] = (_Float16)(e1 * 0.03125f);
        ph[2] = (_Float16)(e2 * 0.03125f); ph[3] = (_Float16)(e3 * 0.03125f);
        puh[t] = ph;
        half4v pv0 = *(const half4v*)(vb + (cg +  0) * 16 + vro);
        half4v pv1 = *(const half4v*)(vb + (cg + 16) * 16 + vro);
        half4v pv2 = *(const half4v*)(vb + (cg + 32) * 16 + vro);
        half4v pv3 = *(const half4v*)(vb + (cg + 48) * 16 + vro);
        __builtin_amdgcn_s_setprio(1);
        oa0 = __builtin_amdgcn_mfma_f32_16x16x16f16(ph, pv0, oa0, 0, 0, 0);
        oa1 = __builtin_amdgcn_mfma_f32_16x16x16f16(ph, pv1, oa1, 0, 0, 0);
        oa2 = __builtin_amdgcn_mfma_f32_16x16x16f16(ph, pv2, oa2, 0, 0, 0);
        oa3 = __builtin_amdgcn_mfma_f32_16x16x16f16(ph, pv3, oa3, 0, 0, 0);
        __builtin_amdgcn_s_setprio(0);
    }

    // ---------------- l reduce (cross-wave: keys are split) ----------------
    ls += __shfl_xor(ls, 16);
    ls += __shfl_xor(ls, 32);
    if (grp == 0) lpart[w][cg] = ls;
    __syncthreads();                      // full fence; closes loop-1 LDS use
    float lt = (lpart[0][cg] + lpart[1][cg]) + (lpart[2][cg] + lpart[3][cg]);
    float rl = 32.0f / lt;                // folds the 2^-5 e-scale
    if (w == 0 && grp == 0) rls[cg] = rl;

    // ---------------- O reduce across waves + ho store ----------------
    float* ored = (float*)(arena + 8192);
    float* orw  = ored + w * (16 * 68);
#pragma unroll
    for (int r = 0; r < 4; ++r) {
        orw[(grp * 4 + r) * 68 +  0 + cg] = oa0[r];
        orw[(grp * 4 + r) * 68 + 16 + cg] = oa1[r];
        orw[(grp * 4 + r) * 68 + 32 + cg] = oa2[r];
        orw[(grp * 4 + r) * 68 + 48 + cg] = oa3[r];
    }
    __syncthreads();
    {
        int qr = tid >> 4, d4 = (tid & 15) * 4;
        float4v s0 = *(const float4v*)(ored + 0 * 1088 + qr * 68 + d4);
        float4v s1 = *(const float4v*)(ored + 1 * 1088 + qr * 68 + d4);
        float4v s2 = *(const float4v*)(ored + 2 * 1088 + qr * 68 + d4);
        float4v s3 = *(const float4v*)(ored + 3 * 1088 + qr * 68 + d4);
        float rlo = rls[qr];
        float4v oo;
        oo[0] = ((s0[0] + s1[0]) + (s2[0] + s3[0])) * rlo;
        oo[1] = ((s0[1] + s1[1]) + (s2[1] + s3[1])) * rlo;
        oo[2] = ((s0[2] + s1[2]) + (s2[2] + s3[2])) * rlo;
        oo[3] = ((s0[3] + s1[3]) + (s2[3] + s3[3])) * rlo;
        __builtin_nontemporal_store(oo, (float4v*)(out_ho + ((size_t)bh * L + q0 + qr) * D + d4));
    }

    // ---------------- loop 2: attn stores ----------------
    float* arow = out_attn + ((size_t)bh * L + q0) * L;
    float* t32f = (float*)arena;                       // dbuf [2][16][64]
    const int c_w   = (w * 4 + grp) ^ (cg & 7);
    const int t32wo = cg * 64 + c_w * 4;
    const int swrow = tid >> 4, jj = tid & 15;
    const int t32ro = swrow * 64 + ((jj ^ (swrow & 7)) * 4);

#pragma unroll
    for (int t = 0; t < NT; ++t) {
        float* tb = t32f + (t & 1) * 1024;
        float4v pn;
        pn[0] = (float)puh[t][0] * rl; pn[1] = (float)puh[t][1] * rl;
        pn[2] = (float)puh[t][2] * rl; pn[3] = (float)puh[t][3] * rl;
        *(float4v*)(tb + t32wo) = pn;
        WAITL();
        BAR();
        float4v s = *(const float4v*)(tb + t32ro);
        __builtin_nontemporal_store(s, (float4v*)(arow + (size_t)swrow * L + t * KT + jj * 4));
    }
}

extern "C" void kernel_launch(void* const* d_in, const int* in_sizes, int n_in,
                              void* d_out, int out_size, void* d_ws, size_t ws_size,
                              hipStream_t stream) {
    const float* q    = (const float*)d_in[0];
    const float* k    = (const float*)d_in[1];
    const float* v    = (const float*)d_in[2];
    const int*   mask = (const int*)d_in[3];
    const float* bias = (const float*)d_in[4];

    float* ho   = (float*)d_out;
    float* attn = (float*)d_out + (size_t)NB * NH * L * D;

    char* ws = (char*)d_ws;
    _Float16* qh  = (_Float16*)(ws);                       //  8 MB
    _Float16* kh  = (_Float16*)(ws + ((size_t)8  << 20));  //  8 MB
    _Float16* vt  = (_Float16*)(ws + ((size_t)16 << 20));  //  8 MB (tiled)
    _Float16* mbh = (_Float16*)(ws + ((size_t)24 << 20));  // 16.8 MB (tiled)
    (void)in_sizes; (void)n_in; (void)out_size; (void)ws_size;

    prep_qk<<<2048, 256, 0, stream>>>(q, k, qh, kh);
    prep_vt<<<1024, 256, 0, stream>>>(v, vt);
    prep_mbh<<<256, 256, 0, stream>>>(mask, bias, mbh);
    attn_fused<<<4096, 256, 0, stream>>>(qh, kh, vt, mbh, ho, attn);
}

// Round 13
// 192.157 us; speedup vs baseline: 1.5195x; 1.0805x over previous
//
#include <hip/hip_runtime.h>

#define L  2048
#define D  64
#define NH 16
#define NB 2
#define KT 64
#define NT 32
#define LOG2E 1.44269504088896f

using half8   = _Float16 __attribute__((ext_vector_type(8)));
using half4v  = _Float16 __attribute__((ext_vector_type(4)));
using float4v = float    __attribute__((ext_vector_type(4)));
using int4v   = int      __attribute__((ext_vector_type(4)));

#define BAR()    asm volatile("s_barrier" ::: "memory")
#define WAITV(n) asm volatile("s_waitcnt vmcnt(" #n ")" ::: "memory")
#define WAITL()  asm volatile("s_waitcnt lgkmcnt(0)" ::: "memory")

__device__ __forceinline__ void gload16(const void* g, void* l) {
    __builtin_amdgcn_global_load_lds((const __attribute__((address_space(1))) void*)g,
                                     (__attribute__((address_space(3))) void*)l, 16, 0, 0);
}
__device__ __forceinline__ void gload4(const void* g, void* l) {
    __builtin_amdgcn_global_load_lds((const __attribute__((address_space(1))) void*)g,
                                     (__attribute__((address_space(3))) void*)l, 4, 0, 0);
}

// ---------------- precompute: qh = fp16(q * log2e/8), kh = fp16(k) ----------------
__global__ __launch_bounds__(256) void prep_qk(const float* __restrict__ q,
                                               const float* __restrict__ k,
                                               _Float16* __restrict__ qh,
                                               _Float16* __restrict__ kh) {
    int i = (blockIdx.x * 256 + threadIdx.x) * 8;
    float4v a0 = *(const float4v*)(q + i);
    float4v a1 = *(const float4v*)(q + i + 4);
    float4v b0 = *(const float4v*)(k + i);
    float4v b1 = *(const float4v*)(k + i + 4);
    half8 qo, ko;
    const float s = 0.125f * LOG2E;
#pragma unroll
    for (int j = 0; j < 4; ++j) {
        qo[j]     = (_Float16)(a0[j] * s);
        qo[4 + j] = (_Float16)(a1[j] * s);
        ko[j]     = (_Float16)b0[j];
        ko[4 + j] = (_Float16)b1[j];
    }
    *(half8*)(qh + i) = qo;
    *(half8*)(kh + i) = ko;
}

// ------- precompute: vt2[bh][kb(128)][d(64)][kl(16)] = fp16(v[b,h,kb*16+kl,d]) -------
__global__ __launch_bounds__(256) void prep_vt(const float* __restrict__ v,
                                               _Float16* __restrict__ vt) {
    __shared__ float tile[64][65];
    int bh = blockIdx.x >> 5;
    int l0 = (blockIdx.x & 31) * 64;
    const float* vb = v + (size_t)bh * L * D + (size_t)l0 * D;
    int row = threadIdx.x >> 2, c0 = (threadIdx.x & 3) * 16;
#pragma unroll
    for (int j = 0; j < 16; j += 4) {
        float4v t4 = *(const float4v*)(vb + row * D + c0 + j);
        tile[row][c0 + j + 0] = t4[0];
        tile[row][c0 + j + 1] = t4[1];
        tile[row][c0 + j + 2] = t4[2];
        tile[row][c0 + j + 3] = t4[3];
    }
    __syncthreads();
    int d = threadIdx.x >> 2, kbl = threadIdx.x & 3;
    int lq = kbl * 16;
    _Float16* ob = vt + (((size_t)bh * 128 + (l0 >> 4) + kbl) * 64 + d) * 16;
    half8 o0, o1;
#pragma unroll
    for (int j = 0; j < 8; ++j) {
        o0[j] = (_Float16)tile[lq + j][d];
        o1[j] = (_Float16)tile[lq + 8 + j][d];
    }
    *(half8*)(ob)     = o0;
    *(half8*)(ob + 8) = o1;
}

// ------- precompute: mbh2[b][qt(128)][t(32)][w(4)][row(16)][kl(16)] -------
// 2048 blocks (bq x 8 t-groups): 8 blocks/CU parallelism (was 256 = 1/CU).
__global__ __launch_bounds__(256) void prep_mbh(const int* __restrict__ mask,
                                                const float* __restrict__ bias,
                                                _Float16* __restrict__ mbh) {
    int blk = blockIdx.x;
    int bq = blk >> 3, tg = blk & 7;
    int b  = bq >> 7, qt = bq & 127;
    int row = threadIdx.x >> 4;             // 0..15
    int c16 = threadIdx.x & 15;             // 4-key chunk within 64-key tile
    const int*   mrow = mask + ((size_t)b * L + qt * 16 + row) * L;
    const float* brow = bias + ((size_t)b * L + qt * 16 + row) * L;
    _Float16* obase = mbh + (size_t)bq * 32768 + (c16 >> 2) * 256 + row * 16 + (c16 & 3) * 4;
#pragma unroll
    for (int tt = 0; tt < 4; ++tt) {
        int t = tg * 4 + tt;
        int key = t * 64 + c16 * 4;
        int4v   m  = *(const int4v*)(mrow + key);
        float4v bb = *(const float4v*)(brow + key);
        half4v o;
        o[0] = m[0] ? (_Float16)(bb[0] * LOG2E) : (_Float16)(-1500.0f);
        o[1] = m[1] ? (_Float16)(bb[1] * LOG2E) : (_Float16)(-1500.0f);
        o[2] = m[2] ? (_Float16)(bb[2] * LOG2E) : (_Float16)(-1500.0f);
        o[3] = m[3] ? (_Float16)(bb[3] * LOG2E) : (_Float16)(-1500.0f);
        *(half4v*)(obase + t * 1024) = o;
    }
}

// ---------------- fused attention (R12 loop 1; loop 2 at 4 tiles/phase) ----------------
__global__ __launch_bounds__(256, 4) void attn_fused(const _Float16* __restrict__ qh,
                                                     const _Float16* __restrict__ kh,
                                                     const _Float16* __restrict__ vt,
                                                     const _Float16* __restrict__ mbh,
                                                     float* __restrict__ out_ho,
                                                     float* __restrict__ out_attn) {
    // loop1: [0,16K) kbuf [w][bs][16key x 64d] | [16K,32K) vbuf [w][bs][64d x 16kl]
    //        [32K,36K) mbuf [w][bs][16row x 16kl]
    // epilogue: ored [4][16][68] f32 at [8K,25.4K)
    // loop2:  t32 dbuf [2][16][256] f32 at [0,32K)
    __shared__ __align__(16) char arena[36864];
    __shared__ float lpart[4][16];
    __shared__ float rls[16];

    int p  = blockIdx.x;                  // XCD x: 4 heads of one b, all q-tiles
    int l  = (p & 7) * 512 + (p >> 3);
    int b  = l >> 11, h = (l >> 7) & 15, qt = l & 127;
    int bh = b * NH + h;
    int q0 = qt * 16;

    int tid = threadIdx.x, w = tid >> 6, lane = tid & 63;
    int cg = lane & 15, grp = lane >> 4;

    const _Float16* kg = kh  + (size_t)bh * L * D;             // [l][d]
    const _Float16* vg = vt  + (size_t)bh * 131072;            // [kb][d][kl]
    const _Float16* mg = mbh + (size_t)(b * 128 + qt) * 32768; // [t][w][row][kl]
    const _Float16* qg = qh  + ((size_t)bh * L + q0) * D;

    half8 aq0 = *(const half8*)(qg + cg * D + grp * 8);
    half8 aq1 = *(const half8*)(qg + cg * D + 32 + grp * 8);

    _Float16* kbw = (_Float16*)(arena)         + w * 2048;
    _Float16* vbw = (_Float16*)(arena + 16384) + w * 2048;
    _Float16* mbw = (_Float16*)(arena + 32768) + w * 512;

    const int r8  = lane >> 3;
    const int kch = ((lane & 7) ^ r8) * 8;        // K src d-chunk, XOR-preswizzled

    auto stage = [&](int t, int bs) {
        int kb = t * 4 + w;
        int k0 = kb * 16;
        _Float16* kd = kbw + bs * 1024;
        gload16(kg + (size_t)(k0 +     r8) * D + kch, kd);
        gload16(kg + (size_t)(k0 + 8 + r8) * D + kch, kd + 512);
        _Float16* vd = vbw + bs * 1024;
        const _Float16* vs = vg + (size_t)kb * 1024;
        gload16(vs + lane * 8, vd);
        gload16(vs + 512 + lane * 8, vd + 512);
        _Float16* md = mbw + bs * 256;
        const _Float16* ms = mg + (size_t)t * 1024 + w * 256;
        gload4(ms + lane * 2, md);
        gload4(ms + 128 + lane * 2, md + 128);
    };

    const int kro = cg * 64;
    const int ks0 = ((grp)     ^ (cg & 7)) * 8;
    const int ks1 = ((4 + grp) ^ (cg & 7)) * 8;
    const int mro = cg * 16 + grp * 4;
    const int vro = grp * 4;

    half4v puh[NT];                               // unnormalized e * 2^-5
    float ls = 0.f;
    float4v oa0 = {0.f,0.f,0.f,0.f}, oa1 = {0.f,0.f,0.f,0.f};
    float4v oa2 = {0.f,0.f,0.f,0.f}, oa3 = {0.f,0.f,0.f,0.f};

    // ---------------- loop 1: barrier-free QK + PV ----------------
    stage(0, 0);
#pragma unroll
    for (int t = 0; t < NT; ++t) {
        const int bs = t & 1;
        if (t + 1 < NT) { stage(t + 1, bs ^ 1); WAITV(6); }
        else            { WAITV(0); }
        const _Float16* kb = kbw + bs * 1024;
        const _Float16* mb = mbw + bs * 256;
        const _Float16* vb = vbw + bs * 1024;
        half8  bk0 = *(const half8*)(kb + kro + ks0);
        half8  bk1 = *(const half8*)(kb + kro + ks1);
        half4v m4  = *(const half4v*)(mb + mro);
        float4v acc;
        acc[0] = (float)m4[0]; acc[1] = (float)m4[1];
        acc[2] = (float)m4[2]; acc[3] = (float)m4[3];
        __builtin_amdgcn_s_setprio(1);
        acc = __builtin_amdgcn_mfma_f32_16x16x32_f16(bk0, aq0, acc, 0, 0, 0);
        acc = __builtin_amdgcn_mfma_f32_16x16x32_f16(bk1, aq1, acc, 0, 0, 0);
        __builtin_amdgcn_s_setprio(0);
        float e0 = exp2f(acc[0]), e1 = exp2f(acc[1]);
        float e2 = exp2f(acc[2]), e3 = exp2f(acc[3]);
        ls += (e0 + e1) + (e2 + e3);
        half4v ph;
        ph[0] = (_Float16)(e0 * 0.03125f); ph[1] = (_Float16)(e1 * 0.03125f);
        ph[2] = (_Float16)(e2 * 0.03125f); ph[3] = (_Float16)(e3 * 0.03125f);
        puh[t] = ph;
        half4v pv0 = *(const half4v*)(vb + (cg +  0) * 16 + vro);
        half4v pv1 = *(const half4v*)(vb + (cg + 16) * 16 + vro);
        half4v pv2 = *(const half4v*)(vb + (cg + 32) * 16 + vro);
        half4v pv3 = *(const half4v*)(vb + (cg + 48) * 16 + vro);
        __builtin_amdgcn_s_setprio(1);
        oa0 = __builtin_amdgcn_mfma_f32_16x16x16f16(ph, pv0, oa0, 0, 0, 0);
        oa1 = __builtin_amdgcn_mfma_f32_16x16x16f16(ph, pv1, oa1, 0, 0, 0);
        oa2 = __builtin_amdgcn_mfma_f32_16x16x16f16(ph, pv2, oa2, 0, 0, 0);
        oa3 = __builtin_amdgcn_mfma_f32_16x16x16f16(ph, pv3, oa3, 0, 0, 0);
        __builtin_amdgcn_s_setprio(0);
    }

    // ---------------- l reduce ----------------
    ls += __shfl_xor(ls, 16);
    ls += __shfl_xor(ls, 32);
    if (grp == 0) lpart[w][cg] = ls;
    __syncthreads();
    float lt = (lpart[0][cg] + lpart[1][cg]) + (lpart[2][cg] + lpart[3][cg]);
    float rl = 32.0f / lt;
    if (w == 0 && grp == 0) rls[cg] = rl;

    // ---------------- O reduce across waves + ho store ----------------
    float* ored = (float*)(arena + 8192);
    float* orw  = ored + w * (16 * 68);
#pragma unroll
    for (int r = 0; r < 4; ++r) {
        orw[(grp * 4 + r) * 68 +  0 + cg] = oa0[r];
        orw[(grp * 4 + r) * 68 + 16 + cg] = oa1[r];
        orw[(grp * 4 + r) * 68 + 32 + cg] = oa2[r];
        orw[(grp * 4 + r) * 68 + 48 + cg] = oa3[r];
    }
    __syncthreads();
    {
        int qr = tid >> 4, d4 = (tid & 15) * 4;
        float4v s0 = *(const float4v*)(ored + 0 * 1088 + qr * 68 + d4);
        float4v s1 = *(const float4v*)(ored + 1 * 1088 + qr * 68 + d4);
        float4v s2 = *(const float4v*)(ored + 2 * 1088 + qr * 68 + d4);
        float4v s3 = *(const float4v*)(ored + 3 * 1088 + qr * 68 + d4);
        float rlo = rls[qr];
        float4v oo;
        oo[0] = ((s0[0] + s1[0]) + (s2[0] + s3[0])) * rlo;
        oo[1] = ((s0[1] + s1[1]) + (s2[1] + s3[1])) * rlo;
        oo[2] = ((s0[2] + s1[2]) + (s2[2] + s3[2])) * rlo;
        oo[3] = ((s0[3] + s1[3]) + (s2[3] + s3[3])) * rlo;
        __builtin_nontemporal_store(oo, (float4v*)(out_ho + ((size_t)bh * L + q0 + qr) * D + d4));
    }
    __syncthreads();                       // ored readers done before t32 overwrites

    // ---------------- loop 2: attn stores, 4 tiles (256 keys) per phase ----------------
    float* arow = out_attn + ((size_t)bh * L + q0) * L;
    float* t32f = (float*)arena;                       // dbuf [2][16][256] f32
    const int gbase = w * 4 + grp;                     // write granule base (per tile i: i*16+gbase)
    const int swrow = tid >> 4, jj = tid & 15;

#pragma unroll
    for (int ph = 0; ph < 8; ++ph) {
        float* tb = t32f + (ph & 1) * 4096;
        // write: 4 tiles' normalized pn, granule-swizzled g^(row&7)
#pragma unroll
        for (int i = 0; i < 4; ++i) {
            const int tt = ph * 4 + i;
            float4v pn;
            pn[0] = (float)puh[tt][0] * rl; pn[1] = (float)puh[tt][1] * rl;
            pn[2] = (float)puh[tt][2] * rl; pn[3] = (float)puh[tt][3] * rl;
            int g = (i * 16 + gbase) ^ (cg & 7);
            *(float4v*)(tb + cg * 256 + g * 4) = pn;
        }
        WAITL();
        BAR();
        // read + NT store: row swrow, 4 x 256B-contiguous segments
#pragma unroll
        for (int k = 0; k < 4; ++k) {
            int g = (jj + 16 * k) ^ (swrow & 7);
            float4v s = *(const float4v*)(tb + swrow * 256 + g * 4);
            __builtin_nontemporal_store(s,
                (float4v*)(arow + (size_t)swrow * L + ph * 256 + (jj + 16 * k) * 4));
        }
    }
}

extern "C" void kernel_launch(void* const* d_in, const int* in_sizes, int n_in,
                              void* d_out, int out_size, void* d_ws, size_t ws_size,
                              hipStream_t stream) {
    const float* q    = (const float*)d_in[0];
    const float* k    = (const float*)d_in[1];
    const float* v    = (const float*)d_in[2];
    const int*   mask = (const int*)d_in[3];
    const float* bias = (const float*)d_in[4];

    float* ho   = (float*)d_out;
    float* attn = (float*)d_out + (size_t)NB * NH * L * D;

    char* ws = (char*)d_ws;
    _Float16* qh  = (_Float16*)(ws);                       //  8 MB
    _Float16* kh  = (_Float16*)(ws + ((size_t)8  << 20));  //  8 MB
    _Float16* vt  = (_Float16*)(ws + ((size_t)16 << 20));  //  8 MB (tiled)
    _Float16* mbh = (_Float16*)(ws + ((size_t)24 << 20));  // 16.8 MB (tiled)
    (void)in_sizes; (void)n_in; (void)out_size; (void)ws_size;

    prep_qk<<<2048, 256, 0, stream>>>(q, k, qh, kh);
    prep_vt<<<1024, 256, 0, stream>>>(v, vt);
    prep_mbh<<<2048, 256, 0, stream>>>(mask, bias, mbh);
    attn_fused<<<4096, 256, 0, stream>>>(qh, kh, vt, mbh, ho, attn);
}